// Round 23
// baseline (60.967 us; speedup 1.0000x reference)
//
#include <hip/hip_runtime.h>
#include <hip/hip_bf16.h>
#include <math.h>

#define BATCH 4
#define SEQ   2048
#define DIM   1024
#define HEAD  64
#define NCHUNK ((BATCH * SEQ * SEQ) / 64)   // 262144 64-bool chunks

typedef __attribute__((ext_vector_type(8))) short bf16x8;
typedef __attribute__((ext_vector_type(4))) short bf16x4;
typedef __attribute__((ext_vector_type(4))) float f32x4;

static __device__ __forceinline__ short f2bf(float f) {
    __hip_bfloat16 h = __float2bfloat16(f);     // RNE
    return *reinterpret_cast<short*>(&h);
}

// volatile asm load: cannot be sunk/serialized by the scheduler; issues into
// the HW vmem queue in program order.
#define GLOAD4(dst, addr) \
    asm volatile("global_load_dwordx4 %0, %1, off" : "=v"(dst) : "v"(addr))

// ---------------------------------------------------------------------------
// Prelude: W[1024][64] f32 -> frag-major Wt2[which][k/32][64][32] bf16, so a
// proj wave's B-frag load (n,c,g lanes) is one contiguous 1KB segment.
// Plus mask dtype detect (int32 bools are {0,1}; byte-bools read as u32
// exceed 1 w.p. 7/8 per word).
// ---------------------------------------------------------------------------
__global__ __launch_bounds__(256) void wconv_detect_kernel(
    const float* __restrict__ Wq, const float* __restrict__ Wk, const float* __restrict__ Wv,
    short* __restrict__ Wt, const unsigned int* __restrict__ mask_u32,
    int* __restrict__ mflag)
{
    const int which = blockIdx.y;
    const float* __restrict__ W = (which == 0) ? Wq : (which == 1) ? Wk : Wv;
    short* __restrict__ Wtw = Wt + (size_t)which * HEAD * DIM;

    const int h  = threadIdx.x & 63;
    const int k0 = blockIdx.x * 64 + (threadIdx.x >> 6) * 16;
    #pragma unroll
    for (int j = 0; j < 16; ++j) {
        int k = k0 + j;
        Wtw[((size_t)(k >> 5) * 64 + h) * 32 + (k & 31)] =
            f2bf(W[(size_t)k * HEAD + h]);
    }

    if (blockIdx.x == 0 && blockIdx.y == 0 && threadIdx.x < 64) {
        int lane = threadIdx.x;
        bool weird = false;
        for (int i = lane; i < 1024; i += 64) weird |= (mask_u32[i] > 1u);
        unsigned long long b = __ballot(weird);
        if (lane == 0) *mflag = (b != 0ull) ? 1 : 0;
    }
}

// ---------------------------------------------------------------------------
// Fused prep v4: grid 1280 x 256, __launch_bounds__(256,2) (VGPR cap 256).
//   blocks [0,512):   mask bit-pack (unchanged, HBM floor)
//   blocks [512,1280): projection M=32 with INLINE-ASM LOAD ISSUE: all 32
//     loads of a half (16 X dwordx4 + 16 W dwordx4) are volatile asm ->
//     mutually ordered, un-sinkable, issued back-to-back into the HW vmem
//     queue; one s_waitcnt vmcnt(0) asm that REDEFINES all dsts ("+v")
//     fences consumption (rule-18 hazard). 32 outstanding loads/wave vs the
//     ~1-2 the compiler produced across R5-R13 (bounds/sched_barrier/SSA
//     keep-alive all failed; this removes the compiler from load issue).
// ---------------------------------------------------------------------------
__global__ __launch_bounds__(256, 2) void prep_kernel(
    const float* __restrict__ Xq, const float* __restrict__ Xk, const float* __restrict__ Xv,
    const short* __restrict__ Wt, const void* __restrict__ mask,
    const int* __restrict__ mflag, unsigned long long* __restrict__ packed,
    short* __restrict__ Q, short* __restrict__ K, short* __restrict__ Vt)
{
    const int bx  = blockIdx.x;
    const int tid = threadIdx.x;
    const int lane = tid & 63;
    const int w    = tid >> 6;

    if (bx < 512) {
        // ------------------------- mask pack -------------------------
        const int gw = bx * 4 + w;                // 0..2047
        const int c0 = gw * 128;
        const int useByte = *mflag;
        if (useByte) {
            const unsigned char* mb = (const unsigned char*)mask;
            for (int i = 0; i < 8; ++i) {
                unsigned char v[16];
                #pragma unroll
                for (int j = 0; j < 16; ++j)
                    v[j] = mb[(size_t)(c0 + i * 16 + j) * 64 + lane];
                #pragma unroll
                for (int j = 0; j < 16; ++j) {
                    unsigned long long bb = __ballot(v[j] != 0);
                    if (lane == 0) packed[c0 + i * 16 + j] = bb;
                }
            }
        } else {
            const unsigned int* mw = (const unsigned int*)mask;
            for (int i = 0; i < 8; ++i) {
                unsigned int v[16];
                #pragma unroll
                for (int j = 0; j < 16; ++j)
                    v[j] = mw[(size_t)(c0 + i * 16 + j) * 64 + lane];
                #pragma unroll
                for (int j = 0; j < 16; ++j) {
                    unsigned long long bb = __ballot(v[j] != 0);
                    if (lane == 0) packed[c0 + i * 16 + j] = bb;
                }
            }
        }
        return;
    }

    // ------------------- projection (M32, asm-issued loads) -------------------
    __shared__ float O_lds[4][32][64];          // [wave][row][col] partials, 32KB

    const int pi    = bx - 512;                 // 0..767
    const int which = pi >> 8;                  // 0:Q 1:K 2:V (256 blocks each)
    const int row0  = (pi & 255) * 32;          // global row (b*S+s)
    const float* __restrict__ X = (which == 0) ? Xq : (which == 1) ? Xk : Xv;
    const short* __restrict__ Wtw = Wt + (size_t)which * HEAD * DIM;

    const int g = lane >> 4;
    const int c = lane & 15;

    const float* __restrict__ Xp0 = X + (size_t)(row0 + c) * DIM + w * 256 + g * 8;
    const float* __restrict__ Xp1 = Xp0 + (size_t)16 * DIM;
    const short* __restrict__ Wp  = Wtw + (size_t)(w * 8) * 2048 + c * 32 + g * 8;

    f32x4 acc0[4], acc1[4];
    #pragma unroll
    for (int n = 0; n < 4; ++n) { acc0[n] = (f32x4)0.0f; acc1[n] = (f32x4)0.0f; }

    #pragma unroll
    for (int half = 0; half < 2; ++half) {
        f32x4 xa0[4], xb0[4], xa1[4], xb1[4];
        bf16x8 wf[16];
        // --- issue all 32 loads back-to-back (volatile asm: un-sinkable) ---
        #pragma unroll
        for (int s = 0; s < 4; ++s) {
            GLOAD4(xa0[s], Xp0 + half * 128 + s * 32);
            GLOAD4(xb0[s], Xp0 + half * 128 + s * 32 + 4);
            GLOAD4(xa1[s], Xp1 + half * 128 + s * 32);
            GLOAD4(xb1[s], Xp1 + half * 128 + s * 32 + 4);
        }
        #pragma unroll
        for (int s = 0; s < 4; ++s)
            #pragma unroll
            for (int n = 0; n < 4; ++n)
                GLOAD4(wf[s * 4 + n], Wp + (size_t)(half * 4 + s) * 2048 + n * 512);
        // --- drain queue; redefine all dsts so no use floats above the wait ---
        asm volatile("s_waitcnt vmcnt(0)"
                     : "+v"(xa0[0]), "+v"(xb0[0]), "+v"(xa1[0]), "+v"(xb1[0]),
                       "+v"(xa0[1]), "+v"(xb0[1]), "+v"(xa1[1]), "+v"(xb1[1]),
                       "+v"(xa0[2]), "+v"(xb0[2]), "+v"(xa1[2]), "+v"(xb1[2]),
                       "+v"(xa0[3]), "+v"(xb0[3]), "+v"(xa1[3]), "+v"(xb1[3]));
        asm volatile(""
                     : "+v"(wf[0]), "+v"(wf[1]), "+v"(wf[2]), "+v"(wf[3]),
                       "+v"(wf[4]), "+v"(wf[5]), "+v"(wf[6]), "+v"(wf[7]),
                       "+v"(wf[8]), "+v"(wf[9]), "+v"(wf[10]), "+v"(wf[11]),
                       "+v"(wf[12]), "+v"(wf[13]), "+v"(wf[14]), "+v"(wf[15]));
        __builtin_amdgcn_sched_barrier(0);
        // --- compute ---
        #pragma unroll
        for (int s = 0; s < 4; ++s) {
            bf16x8 a0, a1;
            a0[0]=f2bf(xa0[s][0]); a0[1]=f2bf(xa0[s][1]); a0[2]=f2bf(xa0[s][2]); a0[3]=f2bf(xa0[s][3]);
            a0[4]=f2bf(xb0[s][0]); a0[5]=f2bf(xb0[s][1]); a0[6]=f2bf(xb0[s][2]); a0[7]=f2bf(xb0[s][3]);
            a1[0]=f2bf(xa1[s][0]); a1[1]=f2bf(xa1[s][1]); a1[2]=f2bf(xa1[s][2]); a1[3]=f2bf(xa1[s][3]);
            a1[4]=f2bf(xb1[s][0]); a1[5]=f2bf(xb1[s][1]); a1[6]=f2bf(xb1[s][2]); a1[7]=f2bf(xb1[s][3]);
            #pragma unroll
            for (int n = 0; n < 4; ++n) {
                acc0[n] = __builtin_amdgcn_mfma_f32_16x16x32_bf16(a0, wf[s * 4 + n],
                                                                  acc0[n], 0, 0, 0);
                acc1[n] = __builtin_amdgcn_mfma_f32_16x16x32_bf16(a1, wf[s * 4 + n],
                                                                  acc1[n], 0, 0, 0);
            }
        }
    }

    // publish partials: C/D layout col = lane&15 (W col), row = g*4+reg (X row)
    #pragma unroll
    for (int n = 0; n < 4; ++n)
        #pragma unroll
        for (int r = 0; r < 4; ++r) {
            O_lds[w][g * 4 + r][n * 16 + c]      = acc0[n][r];
            O_lds[w][16 + g * 4 + r][n * 16 + c] = acc1[n][r];
        }
    __syncthreads();

    if (which < 2) {
        short* dst = (which == 0) ? Q : K;
        const int trow = tid >> 3, c8 = (tid & 7) * 8;   // 32 rows x 8 cols
        f32x4 sA = *(const f32x4*)&O_lds[0][trow][c8];
        f32x4 sB = *(const f32x4*)&O_lds[0][trow][c8 + 4];
        #pragma unroll
        for (int i = 1; i < 4; ++i) {
            f32x4 tA = *(const f32x4*)&O_lds[i][trow][c8];
            f32x4 tB = *(const f32x4*)&O_lds[i][trow][c8 + 4];
            #pragma unroll
            for (int j = 0; j < 4; ++j) { sA[j] += tA[j]; sB[j] += tB[j]; }
        }
        bf16x8 pk;
        #pragma unroll
        for (int j = 0; j < 4; ++j) { pk[j] = f2bf(sA[j]); pk[4 + j] = f2bf(sB[j]); }
        *(bf16x8*)&dst[(size_t)(row0 + trow) * HEAD + c8] = pk;
    } else {
        // Vt[b][h][s]: thread owns one h, 8 consecutive s
        const int h = tid & 63, r8 = (tid >> 6) * 8;
        const int b = row0 >> 11, sb = row0 & (SEQ - 1);
        bf16x8 pk;
        #pragma unroll
        for (int j = 0; j < 8; ++j) {
            float v = O_lds[0][r8 + j][h] + O_lds[1][r8 + j][h]
                    + O_lds[2][r8 + j][h] + O_lds[3][r8 + j][h];
            pk[j] = f2bf(v);
        }
        *(bf16x8*)&Vt[((size_t)(b * HEAD + h)) * SEQ + sb + r8] = pk;
    }
}

// ---------------------------------------------------------------------------
// Flash attention v5 (best, ~9 us): 256 blocks x 512 threads. Block = (batch,
// 32 q-rows): bi&3 = batch -> per-XCD L2-resident K/V/Q/packed. Wave w owns
// keys [w*256,(w+1)*256); K/V frags feed two q-tiles. Swapped QK^T, in-lane
// softmax, bit-mask words, defer-max, P->LDS->PV.
// ---------------------------------------------------------------------------
__global__ __launch_bounds__(512, 2) void attn_kernel(
    const short* __restrict__ Q, const short* __restrict__ K, const short* __restrict__ Vt,
    const unsigned int* __restrict__ packed, float* __restrict__ out)
{
    const int bi    = blockIdx.x;
    const int b     = bi & 3;            // XCD-friendly: batch -> XCDs {b, b+4}
    const int qbase = (bi >> 2) * 32;
    const int tid  = threadIdx.x;
    const int lane = tid & 63;
    const int w    = tid >> 6;          // wave 0..7 = key segment
    const int g    = lane >> 4;
    const int c    = lane & 15;

    const short* Qb = Q  + (size_t)(b * SEQ + qbase) * HEAD;
    const short* Kb = K  + (size_t)b * SEQ * HEAD;
    const short* Vb = Vt + (size_t)b * HEAD * SEQ;

    // LDS: P (loop phase, 16KB: 2 tiles) aliases O (merge phase, 32KB).
    __shared__ __align__(16) unsigned char smem[32768 + 1024];
    short (*P_lds)[2][4][16][8] = (short (*)[2][4][16][8])smem; // [wave][tile][kgrp][q][8]
    float (*O_lds)[16][64]      = (float (*)[16][64])smem;      // [wave][q][h]
    float (*M_lds)[16] = (float (*)[16])(smem + 32768);         // [wave][q]
    float (*L_lds)[16] = (float (*)[16])(smem + 32768 + 512);

    // per-lane mask bits: tile0 q = qbase+c, tile1 q = qbase+16+c
    const unsigned int* pw0 = packed + (size_t)(b * SEQ + qbase + c) * 64 + w * 8;
    unsigned int mw0[8], mw1[8];
    #pragma unroll
    for (int i = 0; i < 8; ++i) { mw0[i] = pw0[i]; mw1[i] = pw0[16 * 64 + i]; }

    // Q as B-operand fragments for both tiles
    bf16x8 qb0 = *(const bf16x8*)&Qb[c * HEAD + g * 8];
    bf16x8 qb1 = *(const bf16x8*)&Qb[c * HEAD + 32 + g * 8];
    bf16x8 qc0 = *(const bf16x8*)&Qb[(16 + c) * HEAD + g * 8];
    bf16x8 qc1 = *(const bf16x8*)&Qb[(16 + c) * HEAD + 32 + g * 8];

    float m0 = -INFINITY, l0 = 0.0f, m1 = -INFINITY, l1 = 0.0f;
    f32x4 o0[4], o1[4];
    #pragma unroll
    for (int n = 0; n < 4; ++n) { o0[n] = (f32x4)0.0f; o1[n] = (f32x4)0.0f; }

    const float scale = 0.125f;                    // HEAD^-0.5
    const float LOG2E = 1.44269504088896340736f;

    for (int i = 0; i < 8; ++i) {
        const int kt = w * 8 + i;                  // key tile of 32
        const short* Kt = Kb + (size_t)kt * 32 * HEAD;

        // V^T B-fragments (shared by both q-tiles)
        bf16x8 vb[4];
        #pragma unroll
        for (int n = 0; n < 4; ++n)
            vb[n] = *(const bf16x8*)&Vb[(size_t)(n * 16 + c) * SEQ + kt * 32 + g * 8];

        // K as A-operand (shared by both q-tiles)
        bf16x8 ka00 = *(const bf16x8*)&Kt[c * HEAD + g * 8];
        bf16x8 ka01 = *(const bf16x8*)&Kt[c * HEAD + 32 + g * 8];
        bf16x8 ka10 = *(const bf16x8*)&Kt[(16 + c) * HEAD + g * 8];
        bf16x8 ka11 = *(const bf16x8*)&Kt[(16 + c) * HEAD + 32 + g * 8];

        // ---- both tiles' QK^T (K frags reused) ----
        f32x4 s0t0 = (f32x4)0.0f, s1t0 = (f32x4)0.0f;
        s0t0 = __builtin_amdgcn_mfma_f32_16x16x32_bf16(ka00, qb0, s0t0, 0, 0, 0);
        s0t0 = __builtin_amdgcn_mfma_f32_16x16x32_bf16(ka01, qb1, s0t0, 0, 0, 0);
        s1t0 = __builtin_amdgcn_mfma_f32_16x16x32_bf16(ka10, qb0, s1t0, 0, 0, 0);
        s1t0 = __builtin_amdgcn_mfma_f32_16x16x32_bf16(ka11, qb1, s1t0, 0, 0, 0);
        f32x4 s0t1 = (f32x4)0.0f, s1t1 = (f32x4)0.0f;
        s0t1 = __builtin_amdgcn_mfma_f32_16x16x32_bf16(ka00, qc0, s0t1, 0, 0, 0);
        s0t1 = __builtin_amdgcn_mfma_f32_16x16x32_bf16(ka01, qc1, s0t1, 0, 0, 0);
        s1t1 = __builtin_amdgcn_mfma_f32_16x16x32_bf16(ka10, qc0, s1t1, 0, 0, 0);
        s1t1 = __builtin_amdgcn_mfma_f32_16x16x32_bf16(ka11, qc1, s1t1, 0, 0, 0);

        // ---- per-tile softmax + PV ----
        #pragma unroll
        for (int t = 0; t < 2; ++t) {
            const f32x4 s0 = t ? s0t1 : s0t0;
            const f32x4 s1 = t ? s1t1 : s1t0;
            const unsigned int mw32 = t ? mw1[i] : mw0[i];
            float& m_run = t ? m1 : m0;
            float& l_run = t ? l1 : l0;
            f32x4* o = t ? o1 : o0;

            float sv[8];
            #pragma unroll
            for (int r = 0; r < 4; ++r) {
                sv[r]     = ((mw32 >> (g * 4 + r)) & 1u)      ? -INFINITY : s0[r] * scale;
                sv[4 + r] = ((mw32 >> (16 + g * 4 + r)) & 1u) ? -INFINITY : s1[r] * scale;
            }

            float mx = fmaxf(fmaxf(fmaxf(sv[0], sv[1]), fmaxf(sv[2], sv[3])),
                             fmaxf(fmaxf(sv[4], sv[5]), fmaxf(sv[6], sv[7])));
            mx = fmaxf(mx, __shfl_xor(mx, 16));
            mx = fmaxf(mx, __shfl_xor(mx, 32));

            if (!__all(mx <= m_run + 8.0f)) {
                float mn = fmaxf(m_run, mx);
                float cf = (m_run == mn) ? 1.0f : exp2f((m_run - mn) * LOG2E);
                float cfq[4];
                #pragma unroll
                for (int r = 0; r < 4; ++r)
                    cfq[r] = __shfl(cf, (lane & 48) | (g * 4 + r));
                #pragma unroll
                for (int n = 0; n < 4; ++n)
                    #pragma unroll
                    for (int r = 0; r < 4; ++r) o[n][r] *= cfq[r];
                l_run *= cf;
                m_run = mn;
            }

            const float mb = m_run * LOG2E;
            float p[8];
            #pragma unroll
            for (int j = 0; j < 8; ++j)
                p[j] = (sv[j] <= -1e37f) ? 0.0f : exp2f(sv[j] * LOG2E - mb);
            float rs = ((p[0] + p[1]) + (p[2] + p[3])) + ((p[4] + p[5]) + (p[6] + p[7]));
            rs += __shfl_xor(rs, 16);
            rs += __shfl_xor(rs, 32);
            l_run += rs;

            bf16x4 p0v, p1v;
            #pragma unroll
            for (int r = 0; r < 4; ++r) { p0v[r] = f2bf(p[r]); p1v[r] = f2bf(p[4 + r]); }
            *(bf16x4*)&P_lds[w][t][g >> 1][c][(g & 1) * 4]       = p0v;
            *(bf16x4*)&P_lds[w][t][2 + (g >> 1)][c][(g & 1) * 4] = p1v;
            bf16x8 pa = *(bf16x8*)&P_lds[w][t][g][c][0];
            #pragma unroll
            for (int n = 0; n < 4; ++n)
                o[n] = __builtin_amdgcn_mfma_f32_16x16x32_bf16(pa, vb[n], o[n], 0, 0, 0);
        }
    }

    // ---- merge: tile0 then tile1 through the same 32KB buffer ----
    const int row  = tid >> 5;
    const int col0 = (tid & 31) * 2;
    float* Ob0 = out + (size_t)(b * SEQ + qbase + row) * HEAD;
    float* Ob1 = out + (size_t)(b * SEQ + qbase + 16 + row) * HEAD;

    #pragma unroll
    for (int t = 0; t < 2; ++t) {
        __syncthreads();   // P reads done (t=0) / previous merge reads done (t=1)
        const f32x4* o = t ? o1 : o0;
        #pragma unroll
        for (int n = 0; n < 4; ++n)
            #pragma unroll
            for (int r = 0; r < 4; ++r)
                O_lds[w][g * 4 + r][n * 16 + c] = o[n][r];
        if (lane < 16) {
            M_lds[w][lane] = t ? m1 : m0;
            L_lds[w][lane] = t ? l1 : l0;
        }
        __syncthreads();

        float M = -INFINITY;
        #pragma unroll
        for (int i = 0; i < 8; ++i) M = fmaxf(M, M_lds[i][row]);
        float L = 0.0f, a0 = 0.0f, a1 = 0.0f;
        #pragma unroll
        for (int i = 0; i < 8; ++i) {
            float wgt = exp2f((M_lds[i][row] - M) * LOG2E);
            L  += L_lds[i][row] * wgt;
            a0 += O_lds[i][row][col0]     * wgt;
            a1 += O_lds[i][row][col0 + 1] * wgt;
        }
        float inv = 1.0f / L;
        float* Ob = t ? Ob1 : Ob0;
        Ob[col0]     = a0 * inv;
        Ob[col0 + 1] = a1 * inv;
    }
}

extern "C" void kernel_launch(void* const* d_in, const int* in_sizes, int n_in,
                              void* d_out, int out_size, void* d_ws, size_t ws_size,
                              hipStream_t stream)
{
    // setup_inputs order: key_input, query_input, value_input, mask, Wq, Wk, Wv
    const float* key_in   = (const float*)d_in[0];
    const float* query_in = (const float*)d_in[1];
    const float* value_in = (const float*)d_in[2];
    const void*  mask     = d_in[3];
    const float* Wq = (const float*)d_in[4];
    const float* Wk = (const float*)d_in[5];
    const float* Wv = (const float*)d_in[6];

    char* ws = (char*)d_ws;
    short* Qw  = (short*)ws;                            // 1 MB
    short* Kw  = Qw + (size_t)BATCH * SEQ * HEAD;       // 1 MB
    short* Vtw = Kw + (size_t)BATCH * SEQ * HEAD;       // 1 MB
    unsigned long long* packed =
        (unsigned long long*)(ws + (size_t)3 * BATCH * SEQ * HEAD * sizeof(short));  // 2 MB
    short* Wt  = (short*)((char*)packed + (size_t)NCHUNK * 8);   // 384 KB
    int* mflag = (int*)((char*)Wt + (size_t)3 * HEAD * DIM * sizeof(short));

    wconv_detect_kernel<<<dim3(16, 3), 256, 0, stream>>>(
        Wq, Wk, Wv, Wt, (const unsigned int*)mask, mflag);

    prep_kernel<<<1280, 256, 0, stream>>>(
        query_in, key_in, value_in, Wt, mask, mflag, packed, Qw, Kw, Vtw);

    attn_kernel<<<256, 512, 0, stream>>>(
        Qw, Kw, Vtw, (const unsigned int*)packed, (float*)d_out);
}

// Round 24
// 57.418 us; speedup vs baseline: 1.0618x; 1.0618x over previous
//
#include <hip/hip_runtime.h>
#include <hip/hip_bf16.h>
#include <math.h>

#define BATCH 4
#define SEQ   2048
#define DIM   1024
#define HEAD  64
#define NCHUNK ((BATCH * SEQ * SEQ) / 64)   // 262144 64-bool chunks

typedef __attribute__((ext_vector_type(8))) short bf16x8;
typedef __attribute__((ext_vector_type(4))) short bf16x4;
typedef __attribute__((ext_vector_type(4))) float f32x4;

static __device__ __forceinline__ short f2bf(float f) {
    __hip_bfloat16 h = __float2bfloat16(f);     // RNE
    return *reinterpret_cast<short*>(&h);
}

// ---------------------------------------------------------------------------
// Prelude: W[1024][64] f32 -> frag-major Wt2[which][k/32][64][32] bf16, so a
// proj wave's B-frag load (n,c,g lanes) is one contiguous 1KB segment.
// Plus mask dtype detect (int32 bools are {0,1}; byte-bools read as u32
// exceed 1 w.p. 7/8 per word).
// ---------------------------------------------------------------------------
__global__ __launch_bounds__(256) void wconv_detect_kernel(
    const float* __restrict__ Wq, const float* __restrict__ Wk, const float* __restrict__ Wv,
    short* __restrict__ Wt, const unsigned int* __restrict__ mask_u32,
    int* __restrict__ mflag)
{
    const int which = blockIdx.y;
    const float* __restrict__ W = (which == 0) ? Wq : (which == 1) ? Wk : Wv;
    short* __restrict__ Wtw = Wt + (size_t)which * HEAD * DIM;

    const int h  = threadIdx.x & 63;
    const int k0 = blockIdx.x * 64 + (threadIdx.x >> 6) * 16;
    #pragma unroll
    for (int j = 0; j < 16; ++j) {
        int k = k0 + j;
        Wtw[((size_t)(k >> 5) * 64 + h) * 32 + (k & 31)] =
            f2bf(W[(size_t)k * HEAD + h]);
    }

    if (blockIdx.x == 0 && blockIdx.y == 0 && threadIdx.x < 64) {
        int lane = threadIdx.x;
        bool weird = false;
        for (int i = lane; i < 1024; i += 64) weird |= (mask_u32[i] > 1u);
        unsigned long long b = __ballot(weird);
        if (lane == 0) *mflag = (b != 0ull) ? 1 : 0;
    }
}

// ---------------------------------------------------------------------------
// Fused prep (session-best config, 57.5 us total, reproduced 4x):
// grid 1280 x 256, __launch_bounds__(256,5).
//   blocks [0,512):   mask bit-pack (67 MB stream at HBM floor)
//   blocks [512,1280): projection M=32: 32 rows x 64 cols per block, 4 waves
//                      split-K 256; each W fragment feeds TWO 16-row
//                      A-operands (loads/row 2.0 — measured optimum).
//                      32 KB LDS f32 merge.
// Session evidence (R5-R13, R23): proj is capped ~36 us by per-CU memory
// concurrency for this pattern — bounds/sched_barrier/SSA-asm/inline-asm
// load forcing (VGPR 48->84), counted-vmcnt LDS pipelines, and fusion all
// land at the same rate. M32 register-direct is the empirical optimum.
// ---------------------------------------------------------------------------
__global__ __launch_bounds__(256, 5) void prep_kernel(
    const float* __restrict__ Xq, const float* __restrict__ Xk, const float* __restrict__ Xv,
    const short* __restrict__ Wt, const void* __restrict__ mask,
    const int* __restrict__ mflag, unsigned long long* __restrict__ packed,
    short* __restrict__ Q, short* __restrict__ K, short* __restrict__ Vt)
{
    const int bx  = blockIdx.x;
    const int tid = threadIdx.x;
    const int lane = tid & 63;
    const int w    = tid >> 6;

    if (bx < 512) {
        // ------------------------- mask pack -------------------------
        const int gw = bx * 4 + w;                // 0..2047
        const int c0 = gw * 128;
        const int useByte = *mflag;
        if (useByte) {
            const unsigned char* mb = (const unsigned char*)mask;
            for (int i = 0; i < 8; ++i) {
                unsigned char v[16];
                #pragma unroll
                for (int j = 0; j < 16; ++j)
                    v[j] = mb[(size_t)(c0 + i * 16 + j) * 64 + lane];
                #pragma unroll
                for (int j = 0; j < 16; ++j) {
                    unsigned long long bb = __ballot(v[j] != 0);
                    if (lane == 0) packed[c0 + i * 16 + j] = bb;
                }
            }
        } else {
            const unsigned int* mw = (const unsigned int*)mask;
            for (int i = 0; i < 8; ++i) {
                unsigned int v[16];
                #pragma unroll
                for (int j = 0; j < 16; ++j)
                    v[j] = mw[(size_t)(c0 + i * 16 + j) * 64 + lane];
                #pragma unroll
                for (int j = 0; j < 16; ++j) {
                    unsigned long long bb = __ballot(v[j] != 0);
                    if (lane == 0) packed[c0 + i * 16 + j] = bb;
                }
            }
        }
        return;
    }

    // ------------------- projection (proj5-M32 core) -------------------
    __shared__ float O_lds[4][32][64];          // [wave][row][col] partials, 32KB

    const int pi    = bx - 512;                 // 0..767
    const int which = pi >> 8;                  // 0:Q 1:K 2:V (256 blocks each)
    const int row0  = (pi & 255) * 32;          // global row (b*S+s)
    const float* __restrict__ X = (which == 0) ? Xq : (which == 1) ? Xk : Xv;
    const short* __restrict__ Wtw = Wt + (size_t)which * HEAD * DIM;

    const int g = lane >> 4;
    const int c = lane & 15;

    const float* __restrict__ Xp0 = X + (size_t)(row0 + c) * DIM + w * 256 + g * 8;
    const float* __restrict__ Xp1 = Xp0 + (size_t)16 * DIM;
    const short* __restrict__ Wp  = Wtw + (size_t)(w * 8) * 2048 + c * 32 + g * 8;

    f32x4 acc0[4], acc1[4];
    #pragma unroll
    for (int n = 0; n < 4; ++n) { acc0[n] = (f32x4)0.0f; acc1[n] = (f32x4)0.0f; }

    #pragma unroll
    for (int half = 0; half < 2; ++half) {
        f32x4 xa0[4], xb0[4], xa1[4], xb1[4];
        #pragma unroll
        for (int s = 0; s < 4; ++s) {
            xa0[s] = *(const f32x4*)(Xp0 + half * 128 + s * 32);
            xb0[s] = *(const f32x4*)(Xp0 + half * 128 + s * 32 + 4);
            xa1[s] = *(const f32x4*)(Xp1 + half * 128 + s * 32);
            xb1[s] = *(const f32x4*)(Xp1 + half * 128 + s * 32 + 4);
        }
        bf16x8 wf[16];
        #pragma unroll
        for (int s = 0; s < 4; ++s)
            #pragma unroll
            for (int n = 0; n < 4; ++n)
                wf[s * 4 + n] = *(const bf16x8*)(Wp + (size_t)(half * 4 + s) * 2048
                                                 + n * 512);
        #pragma unroll
        for (int s = 0; s < 4; ++s) {
            bf16x8 a0, a1;
            a0[0]=f2bf(xa0[s][0]); a0[1]=f2bf(xa0[s][1]); a0[2]=f2bf(xa0[s][2]); a0[3]=f2bf(xa0[s][3]);
            a0[4]=f2bf(xb0[s][0]); a0[5]=f2bf(xb0[s][1]); a0[6]=f2bf(xb0[s][2]); a0[7]=f2bf(xb0[s][3]);
            a1[0]=f2bf(xa1[s][0]); a1[1]=f2bf(xa1[s][1]); a1[2]=f2bf(xa1[s][2]); a1[3]=f2bf(xa1[s][3]);
            a1[4]=f2bf(xb1[s][0]); a1[5]=f2bf(xb1[s][1]); a1[6]=f2bf(xb1[s][2]); a1[7]=f2bf(xb1[s][3]);
            #pragma unroll
            for (int n = 0; n < 4; ++n) {
                acc0[n] = __builtin_amdgcn_mfma_f32_16x16x32_bf16(a0, wf[s * 4 + n],
                                                                  acc0[n], 0, 0, 0);
                acc1[n] = __builtin_amdgcn_mfma_f32_16x16x32_bf16(a1, wf[s * 4 + n],
                                                                  acc1[n], 0, 0, 0);
            }
        }
    }

    // publish partials: C/D layout col = lane&15 (W col), row = g*4+reg (X row)
    #pragma unroll
    for (int n = 0; n < 4; ++n)
        #pragma unroll
        for (int r = 0; r < 4; ++r) {
            O_lds[w][g * 4 + r][n * 16 + c]      = acc0[n][r];
            O_lds[w][16 + g * 4 + r][n * 16 + c] = acc1[n][r];
        }
    __syncthreads();

    if (which < 2) {
        short* dst = (which == 0) ? Q : K;
        const int trow = tid >> 3, c8 = (tid & 7) * 8;   // 32 rows x 8 cols
        f32x4 sA = *(const f32x4*)&O_lds[0][trow][c8];
        f32x4 sB = *(const f32x4*)&O_lds[0][trow][c8 + 4];
        #pragma unroll
        for (int i = 1; i < 4; ++i) {
            f32x4 tA = *(const f32x4*)&O_lds[i][trow][c8];
            f32x4 tB = *(const f32x4*)&O_lds[i][trow][c8 + 4];
            #pragma unroll
            for (int j = 0; j < 4; ++j) { sA[j] += tA[j]; sB[j] += tB[j]; }
        }
        bf16x8 pk;
        #pragma unroll
        for (int j = 0; j < 4; ++j) { pk[j] = f2bf(sA[j]); pk[4 + j] = f2bf(sB[j]); }
        *(bf16x8*)&dst[(size_t)(row0 + trow) * HEAD + c8] = pk;
    } else {
        // Vt[b][h][s]: thread owns one h, 8 consecutive s
        const int h = tid & 63, r8 = (tid >> 6) * 8;
        const int b = row0 >> 11, sb = row0 & (SEQ - 1);
        bf16x8 pk;
        #pragma unroll
        for (int j = 0; j < 8; ++j) {
            float v = O_lds[0][r8 + j][h] + O_lds[1][r8 + j][h]
                    + O_lds[2][r8 + j][h] + O_lds[3][r8 + j][h];
            pk[j] = f2bf(v);
        }
        *(bf16x8*)&Vt[((size_t)(b * HEAD + h)) * SEQ + sb + r8] = pk;
    }
}

// ---------------------------------------------------------------------------
// Flash attention v5 (best, ~9 us): 256 blocks x 512 threads. Block = (batch,
// 32 q-rows): bi&3 = batch -> per-XCD L2-resident K/V/Q/packed. Wave w owns
// keys [w*256,(w+1)*256); K/V frags feed two q-tiles. Swapped QK^T, in-lane
// softmax, bit-mask words, defer-max, P->LDS->PV.
// ---------------------------------------------------------------------------
__global__ __launch_bounds__(512, 2) void attn_kernel(
    const short* __restrict__ Q, const short* __restrict__ K, const short* __restrict__ Vt,
    const unsigned int* __restrict__ packed, float* __restrict__ out)
{
    const int bi    = blockIdx.x;
    const int b     = bi & 3;            // XCD-friendly: batch -> XCDs {b, b+4}
    const int qbase = (bi >> 2) * 32;
    const int tid  = threadIdx.x;
    const int lane = tid & 63;
    const int w    = tid >> 6;          // wave 0..7 = key segment
    const int g    = lane >> 4;
    const int c    = lane & 15;

    const short* Qb = Q  + (size_t)(b * SEQ + qbase) * HEAD;
    const short* Kb = K  + (size_t)b * SEQ * HEAD;
    const short* Vb = Vt + (size_t)b * HEAD * SEQ;

    // LDS: P (loop phase, 16KB: 2 tiles) aliases O (merge phase, 32KB).
    __shared__ __align__(16) unsigned char smem[32768 + 1024];
    short (*P_lds)[2][4][16][8] = (short (*)[2][4][16][8])smem; // [wave][tile][kgrp][q][8]
    float (*O_lds)[16][64]      = (float (*)[16][64])smem;      // [wave][q][h]
    float (*M_lds)[16] = (float (*)[16])(smem + 32768);         // [wave][q]
    float (*L_lds)[16] = (float (*)[16])(smem + 32768 + 512);

    // per-lane mask bits: tile0 q = qbase+c, tile1 q = qbase+16+c
    const unsigned int* pw0 = packed + (size_t)(b * SEQ + qbase + c) * 64 + w * 8;
    unsigned int mw0[8], mw1[8];
    #pragma unroll
    for (int i = 0; i < 8; ++i) { mw0[i] = pw0[i]; mw1[i] = pw0[16 * 64 + i]; }

    // Q as B-operand fragments for both tiles
    bf16x8 qb0 = *(const bf16x8*)&Qb[c * HEAD + g * 8];
    bf16x8 qb1 = *(const bf16x8*)&Qb[c * HEAD + 32 + g * 8];
    bf16x8 qc0 = *(const bf16x8*)&Qb[(16 + c) * HEAD + g * 8];
    bf16x8 qc1 = *(const bf16x8*)&Qb[(16 + c) * HEAD + 32 + g * 8];

    float m0 = -INFINITY, l0 = 0.0f, m1 = -INFINITY, l1 = 0.0f;
    f32x4 o0[4], o1[4];
    #pragma unroll
    for (int n = 0; n < 4; ++n) { o0[n] = (f32x4)0.0f; o1[n] = (f32x4)0.0f; }

    const float scale = 0.125f;                    // HEAD^-0.5
    const float LOG2E = 1.44269504088896340736f;

    for (int i = 0; i < 8; ++i) {
        const int kt = w * 8 + i;                  // key tile of 32
        const short* Kt = Kb + (size_t)kt * 32 * HEAD;

        // V^T B-fragments (shared by both q-tiles)
        bf16x8 vb[4];
        #pragma unroll
        for (int n = 0; n < 4; ++n)
            vb[n] = *(const bf16x8*)&Vb[(size_t)(n * 16 + c) * SEQ + kt * 32 + g * 8];

        // K as A-operand (shared by both q-tiles)
        bf16x8 ka00 = *(const bf16x8*)&Kt[c * HEAD + g * 8];
        bf16x8 ka01 = *(const bf16x8*)&Kt[c * HEAD + 32 + g * 8];
        bf16x8 ka10 = *(const bf16x8*)&Kt[(16 + c) * HEAD + g * 8];
        bf16x8 ka11 = *(const bf16x8*)&Kt[(16 + c) * HEAD + 32 + g * 8];

        // ---- both tiles' QK^T (K frags reused) ----
        f32x4 s0t0 = (f32x4)0.0f, s1t0 = (f32x4)0.0f;
        s0t0 = __builtin_amdgcn_mfma_f32_16x16x32_bf16(ka00, qb0, s0t0, 0, 0, 0);
        s0t0 = __builtin_amdgcn_mfma_f32_16x16x32_bf16(ka01, qb1, s0t0, 0, 0, 0);
        s1t0 = __builtin_amdgcn_mfma_f32_16x16x32_bf16(ka10, qb0, s1t0, 0, 0, 0);
        s1t0 = __builtin_amdgcn_mfma_f32_16x16x32_bf16(ka11, qb1, s1t0, 0, 0, 0);
        f32x4 s0t1 = (f32x4)0.0f, s1t1 = (f32x4)0.0f;
        s0t1 = __builtin_amdgcn_mfma_f32_16x16x32_bf16(ka00, qc0, s0t1, 0, 0, 0);
        s0t1 = __builtin_amdgcn_mfma_f32_16x16x32_bf16(ka01, qc1, s0t1, 0, 0, 0);
        s1t1 = __builtin_amdgcn_mfma_f32_16x16x32_bf16(ka10, qc0, s1t1, 0, 0, 0);
        s1t1 = __builtin_amdgcn_mfma_f32_16x16x32_bf16(ka11, qc1, s1t1, 0, 0, 0);

        // ---- per-tile softmax + PV ----
        #pragma unroll
        for (int t = 0; t < 2; ++t) {
            const f32x4 s0 = t ? s0t1 : s0t0;
            const f32x4 s1 = t ? s1t1 : s1t0;
            const unsigned int mw32 = t ? mw1[i] : mw0[i];
            float& m_run = t ? m1 : m0;
            float& l_run = t ? l1 : l0;
            f32x4* o = t ? o1 : o0;

            float sv[8];
            #pragma unroll
            for (int r = 0; r < 4; ++r) {
                sv[r]     = ((mw32 >> (g * 4 + r)) & 1u)      ? -INFINITY : s0[r] * scale;
                sv[4 + r] = ((mw32 >> (16 + g * 4 + r)) & 1u) ? -INFINITY : s1[r] * scale;
            }

            float mx = fmaxf(fmaxf(fmaxf(sv[0], sv[1]), fmaxf(sv[2], sv[3])),
                             fmaxf(fmaxf(sv[4], sv[5]), fmaxf(sv[6], sv[7])));
            mx = fmaxf(mx, __shfl_xor(mx, 16));
            mx = fmaxf(mx, __shfl_xor(mx, 32));

            if (!__all(mx <= m_run + 8.0f)) {
                float mn = fmaxf(m_run, mx);
                float cf = (m_run == mn) ? 1.0f : exp2f((m_run - mn) * LOG2E);
                float cfq[4];
                #pragma unroll
                for (int r = 0; r < 4; ++r)
                    cfq[r] = __shfl(cf, (lane & 48) | (g * 4 + r));
                #pragma unroll
                for (int n = 0; n < 4; ++n)
                    #pragma unroll
                    for (int r = 0; r < 4; ++r) o[n][r] *= cfq[r];
                l_run *= cf;
                m_run = mn;
            }

            const float mb = m_run * LOG2E;
            float p[8];
            #pragma unroll
            for (int j = 0; j < 8; ++j)
                p[j] = (sv[j] <= -1e37f) ? 0.0f : exp2f(sv[j] * LOG2E - mb);
            float rs = ((p[0] + p[1]) + (p[2] + p[3])) + ((p[4] + p[5]) + (p[6] + p[7]));
            rs += __shfl_xor(rs, 16);
            rs += __shfl_xor(rs, 32);
            l_run += rs;

            bf16x4 p0v, p1v;
            #pragma unroll
            for (int r = 0; r < 4; ++r) { p0v[r] = f2bf(p[r]); p1v[r] = f2bf(p[4 + r]); }
            *(bf16x4*)&P_lds[w][t][g >> 1][c][(g & 1) * 4]       = p0v;
            *(bf16x4*)&P_lds[w][t][2 + (g >> 1)][c][(g & 1) * 4] = p1v;
            bf16x8 pa = *(bf16x8*)&P_lds[w][t][g][c][0];
            #pragma unroll
            for (int n = 0; n < 4; ++n)
                o[n] = __builtin_amdgcn_mfma_f32_16x16x32_bf16(pa, vb[n], o[n], 0, 0, 0);
        }
    }

    // ---- merge: tile0 then tile1 through the same 32KB buffer ----
    const int row  = tid >> 5;
    const int col0 = (tid & 31) * 2;
    float* Ob0 = out + (size_t)(b * SEQ + qbase + row) * HEAD;
    float* Ob1 = out + (size_t)(b * SEQ + qbase + 16 + row) * HEAD;

    #pragma unroll
    for (int t = 0; t < 2; ++t) {
        __syncthreads();   // P reads done (t=0) / previous merge reads done (t=1)
        const f32x4* o = t ? o1 : o0;
        #pragma unroll
        for (int n = 0; n < 4; ++n)
            #pragma unroll
            for (int r = 0; r < 4; ++r)
                O_lds[w][g * 4 + r][n * 16 + c] = o[n][r];
        if (lane < 16) {
            M_lds[w][lane] = t ? m1 : m0;
            L_lds[w][lane] = t ? l1 : l0;
        }
        __syncthreads();

        float M = -INFINITY;
        #pragma unroll
        for (int i = 0; i < 8; ++i) M = fmaxf(M, M_lds[i][row]);
        float L = 0.0f, a0 = 0.0f, a1 = 0.0f;
        #pragma unroll
        for (int i = 0; i < 8; ++i) {
            float wgt = exp2f((M_lds[i][row] - M) * LOG2E);
            L  += L_lds[i][row] * wgt;
            a0 += O_lds[i][row][col0]     * wgt;
            a1 += O_lds[i][row][col0 + 1] * wgt;
        }
        float inv = 1.0f / L;
        float* Ob = t ? Ob1 : Ob0;
        Ob[col0]     = a0 * inv;
        Ob[col0 + 1] = a1 * inv;
    }
}

extern "C" void kernel_launch(void* const* d_in, const int* in_sizes, int n_in,
                              void* d_out, int out_size, void* d_ws, size_t ws_size,
                              hipStream_t stream)
{
    // setup_inputs order: key_input, query_input, value_input, mask, Wq, Wk, Wv
    const float* key_in   = (const float*)d_in[0];
    const float* query_in = (const float*)d_in[1];
    const float* value_in = (const float*)d_in[2];
    const void*  mask     = d_in[3];
    const float* Wq = (const float*)d_in[4];
    const float* Wk = (const float*)d_in[5];
    const float* Wv = (const float*)d_in[6];

    char* ws = (char*)d_ws;
    short* Qw  = (short*)ws;                            // 1 MB
    short* Kw  = Qw + (size_t)BATCH * SEQ * HEAD;       // 1 MB
    short* Vtw = Kw + (size_t)BATCH * SEQ * HEAD;       // 1 MB
    unsigned long long* packed =
        (unsigned long long*)(ws + (size_t)3 * BATCH * SEQ * HEAD * sizeof(short));  // 2 MB
    short* Wt  = (short*)((char*)packed + (size_t)NCHUNK * 8);   // 384 KB
    int* mflag = (int*)((char*)Wt + (size_t)3 * HEAD * DIM * sizeof(short));

    wconv_detect_kernel<<<dim3(16, 3), 256, 0, stream>>>(
        Wq, Wk, Wv, Wt, (const unsigned int*)mask, mflag);

    prep_kernel<<<1280, 256, 0, stream>>>(
        query_in, key_in, value_in, Wt, mask, mflag, packed, Qw, Kw, Vtw);

    attn_kernel<<<256, 512, 0, stream>>>(
        Qw, Kw, Vtw, (const unsigned int*)packed, (float*)d_out);
}

// Round 25
// 57.340 us; speedup vs baseline: 1.0633x; 1.0014x over previous
//
#include <hip/hip_runtime.h>
#include <hip/hip_bf16.h>
#include <math.h>

#define BATCH 4
#define SEQ   2048
#define DIM   1024
#define HEAD  64
#define NCHUNK ((BATCH * SEQ * SEQ) / 64)   // 262144 64-bool chunks

typedef __attribute__((ext_vector_type(8))) short bf16x8;
typedef __attribute__((ext_vector_type(4))) short bf16x4;
typedef __attribute__((ext_vector_type(4))) float f32x4;

static __device__ __forceinline__ short f2bf(float f) {
    __hip_bfloat16 h = __float2bfloat16(f);     // RNE
    return *reinterpret_cast<short*>(&h);
}

// ---------------------------------------------------------------------------
// Prelude: W[1024][64] f32 -> frag-major Wt2[which][k/32][64][32] bf16, so a
// proj wave's B-frag load (n,c,g lanes) is one contiguous 1KB segment.
// Plus mask dtype detect (int32 bools are {0,1}; byte-bools read as u32
// exceed 1 w.p. 7/8 per word).
// ---------------------------------------------------------------------------
__global__ __launch_bounds__(256) void wconv_detect_kernel(
    const float* __restrict__ Wq, const float* __restrict__ Wk, const float* __restrict__ Wv,
    short* __restrict__ Wt, const unsigned int* __restrict__ mask_u32,
    int* __restrict__ mflag)
{
    const int which = blockIdx.y;
    const float* __restrict__ W = (which == 0) ? Wq : (which == 1) ? Wk : Wv;
    short* __restrict__ Wtw = Wt + (size_t)which * HEAD * DIM;

    const int h  = threadIdx.x & 63;
    const int k0 = blockIdx.x * 64 + (threadIdx.x >> 6) * 16;
    #pragma unroll
    for (int j = 0; j < 16; ++j) {
        int k = k0 + j;
        Wtw[((size_t)(k >> 5) * 64 + h) * 32 + (k & 31)] =
            f2bf(W[(size_t)k * HEAD + h]);
    }

    if (blockIdx.x == 0 && blockIdx.y == 0 && threadIdx.x < 64) {
        int lane = threadIdx.x;
        bool weird = false;
        for (int i = lane; i < 1024; i += 64) weird |= (mask_u32[i] > 1u);
        unsigned long long b = __ballot(weird);
        if (lane == 0) *mflag = (b != 0ull) ? 1 : 0;
    }
}

// ---------------------------------------------------------------------------
// Fused prep (session-best config, 57.5 us total, reproduced 4x):
// grid 1280 x 256, __launch_bounds__(256,5).
//   blocks [0,512):   mask bit-pack (67 MB stream at HBM floor)
//   blocks [512,1280): projection M=32: 32 rows x 64 cols per block, 4 waves
//                      split-K 256; each W fragment feeds TWO 16-row
//                      A-operands (loads/row 2.0 — measured optimum).
//                      32 KB LDS f32 merge.
// Session evidence (R5-R13, R23): proj is capped ~36 us by per-CU memory
// concurrency for this pattern — bounds/sched_barrier/SSA-asm/inline-asm
// load forcing (VGPR 48->84), counted-vmcnt LDS pipelines, and fusion all
// land at the same rate. M32 register-direct is the empirical optimum.
// ---------------------------------------------------------------------------
__global__ __launch_bounds__(256, 5) void prep_kernel(
    const float* __restrict__ Xq, const float* __restrict__ Xk, const float* __restrict__ Xv,
    const short* __restrict__ Wt, const void* __restrict__ mask,
    const int* __restrict__ mflag, unsigned long long* __restrict__ packed,
    short* __restrict__ Q, short* __restrict__ K, short* __restrict__ Vt)
{
    const int bx  = blockIdx.x;
    const int tid = threadIdx.x;
    const int lane = tid & 63;
    const int w    = tid >> 6;

    if (bx < 512) {
        // ------------------------- mask pack -------------------------
        const int gw = bx * 4 + w;                // 0..2047
        const int c0 = gw * 128;
        const int useByte = *mflag;
        if (useByte) {
            const unsigned char* mb = (const unsigned char*)mask;
            for (int i = 0; i < 8; ++i) {
                unsigned char v[16];
                #pragma unroll
                for (int j = 0; j < 16; ++j)
                    v[j] = mb[(size_t)(c0 + i * 16 + j) * 64 + lane];
                #pragma unroll
                for (int j = 0; j < 16; ++j) {
                    unsigned long long bb = __ballot(v[j] != 0);
                    if (lane == 0) packed[c0 + i * 16 + j] = bb;
                }
            }
        } else {
            const unsigned int* mw = (const unsigned int*)mask;
            for (int i = 0; i < 8; ++i) {
                unsigned int v[16];
                #pragma unroll
                for (int j = 0; j < 16; ++j)
                    v[j] = mw[(size_t)(c0 + i * 16 + j) * 64 + lane];
                #pragma unroll
                for (int j = 0; j < 16; ++j) {
                    unsigned long long bb = __ballot(v[j] != 0);
                    if (lane == 0) packed[c0 + i * 16 + j] = bb;
                }
            }
        }
        return;
    }

    // ------------------- projection (proj5-M32 core) -------------------
    __shared__ float O_lds[4][32][64];          // [wave][row][col] partials, 32KB

    const int pi    = bx - 512;                 // 0..767
    const int which = pi >> 8;                  // 0:Q 1:K 2:V (256 blocks each)
    const int row0  = (pi & 255) * 32;          // global row (b*S+s)
    const float* __restrict__ X = (which == 0) ? Xq : (which == 1) ? Xk : Xv;
    const short* __restrict__ Wtw = Wt + (size_t)which * HEAD * DIM;

    const int g = lane >> 4;
    const int c = lane & 15;

    const float* __restrict__ Xp0 = X + (size_t)(row0 + c) * DIM + w * 256 + g * 8;
    const float* __restrict__ Xp1 = Xp0 + (size_t)16 * DIM;
    const short* __restrict__ Wp  = Wtw + (size_t)(w * 8) * 2048 + c * 32 + g * 8;

    f32x4 acc0[4], acc1[4];
    #pragma unroll
    for (int n = 0; n < 4; ++n) { acc0[n] = (f32x4)0.0f; acc1[n] = (f32x4)0.0f; }

    #pragma unroll
    for (int half = 0; half < 2; ++half) {
        f32x4 xa0[4], xb0[4], xa1[4], xb1[4];
        #pragma unroll
        for (int s = 0; s < 4; ++s) {
            xa0[s] = *(const f32x4*)(Xp0 + half * 128 + s * 32);
            xb0[s] = *(const f32x4*)(Xp0 + half * 128 + s * 32 + 4);
            xa1[s] = *(const f32x4*)(Xp1 + half * 128 + s * 32);
            xb1[s] = *(const f32x4*)(Xp1 + half * 128 + s * 32 + 4);
        }
        bf16x8 wf[16];
        #pragma unroll
        for (int s = 0; s < 4; ++s)
            #pragma unroll
            for (int n = 0; n < 4; ++n)
                wf[s * 4 + n] = *(const bf16x8*)(Wp + (size_t)(half * 4 + s) * 2048
                                                 + n * 512);
        #pragma unroll
        for (int s = 0; s < 4; ++s) {
            bf16x8 a0, a1;
            a0[0]=f2bf(xa0[s][0]); a0[1]=f2bf(xa0[s][1]); a0[2]=f2bf(xa0[s][2]); a0[3]=f2bf(xa0[s][3]);
            a0[4]=f2bf(xb0[s][0]); a0[5]=f2bf(xb0[s][1]); a0[6]=f2bf(xb0[s][2]); a0[7]=f2bf(xb0[s][3]);
            a1[0]=f2bf(xa1[s][0]); a1[1]=f2bf(xa1[s][1]); a1[2]=f2bf(xa1[s][2]); a1[3]=f2bf(xa1[s][3]);
            a1[4]=f2bf(xb1[s][0]); a1[5]=f2bf(xb1[s][1]); a1[6]=f2bf(xb1[s][2]); a1[7]=f2bf(xb1[s][3]);
            #pragma unroll
            for (int n = 0; n < 4; ++n) {
                acc0[n] = __builtin_amdgcn_mfma_f32_16x16x32_bf16(a0, wf[s * 4 + n],
                                                                  acc0[n], 0, 0, 0);
                acc1[n] = __builtin_amdgcn_mfma_f32_16x16x32_bf16(a1, wf[s * 4 + n],
                                                                  acc1[n], 0, 0, 0);
            }
        }
    }

    // publish partials: C/D layout col = lane&15 (W col), row = g*4+reg (X row)
    #pragma unroll
    for (int n = 0; n < 4; ++n)
        #pragma unroll
        for (int r = 0; r < 4; ++r) {
            O_lds[w][g * 4 + r][n * 16 + c]      = acc0[n][r];
            O_lds[w][16 + g * 4 + r][n * 16 + c] = acc1[n][r];
        }
    __syncthreads();

    if (which < 2) {
        short* dst = (which == 0) ? Q : K;
        const int trow = tid >> 3, c8 = (tid & 7) * 8;   // 32 rows x 8 cols
        f32x4 sA = *(const f32x4*)&O_lds[0][trow][c8];
        f32x4 sB = *(const f32x4*)&O_lds[0][trow][c8 + 4];
        #pragma unroll
        for (int i = 1; i < 4; ++i) {
            f32x4 tA = *(const f32x4*)&O_lds[i][trow][c8];
            f32x4 tB = *(const f32x4*)&O_lds[i][trow][c8 + 4];
            #pragma unroll
            for (int j = 0; j < 4; ++j) { sA[j] += tA[j]; sB[j] += tB[j]; }
        }
        bf16x8 pk;
        #pragma unroll
        for (int j = 0; j < 4; ++j) { pk[j] = f2bf(sA[j]); pk[4 + j] = f2bf(sB[j]); }
        *(bf16x8*)&dst[(size_t)(row0 + trow) * HEAD + c8] = pk;
    } else {
        // Vt[b][h][s]: thread owns one h, 8 consecutive s
        const int h = tid & 63, r8 = (tid >> 6) * 8;
        const int b = row0 >> 11, sb = row0 & (SEQ - 1);
        bf16x8 pk;
        #pragma unroll
        for (int j = 0; j < 8; ++j) {
            float v = O_lds[0][r8 + j][h] + O_lds[1][r8 + j][h]
                    + O_lds[2][r8 + j][h] + O_lds[3][r8 + j][h];
            pk[j] = f2bf(v);
        }
        *(bf16x8*)&Vt[((size_t)(b * HEAD + h)) * SEQ + sb + r8] = pk;
    }
}

// ---------------------------------------------------------------------------
// Flash attention v5 (best, ~9 us): 256 blocks x 512 threads. Block = (batch,
// 32 q-rows): bi&3 = batch -> per-XCD L2-resident K/V/Q/packed. Wave w owns
// keys [w*256,(w+1)*256); K/V frags feed two q-tiles. Swapped QK^T, in-lane
// softmax, bit-mask words, defer-max, P->LDS->PV.
// ---------------------------------------------------------------------------
__global__ __launch_bounds__(512, 2) void attn_kernel(
    const short* __restrict__ Q, const short* __restrict__ K, const short* __restrict__ Vt,
    const unsigned int* __restrict__ packed, float* __restrict__ out)
{
    const int bi    = blockIdx.x;
    const int b     = bi & 3;            // XCD-friendly: batch -> XCDs {b, b+4}
    const int qbase = (bi >> 2) * 32;
    const int tid  = threadIdx.x;
    const int lane = tid & 63;
    const int w    = tid >> 6;          // wave 0..7 = key segment
    const int g    = lane >> 4;
    const int c    = lane & 15;

    const short* Qb = Q  + (size_t)(b * SEQ + qbase) * HEAD;
    const short* Kb = K  + (size_t)b * SEQ * HEAD;
    const short* Vb = Vt + (size_t)b * HEAD * SEQ;

    // LDS: P (loop phase, 16KB: 2 tiles) aliases O (merge phase, 32KB).
    __shared__ __align__(16) unsigned char smem[32768 + 1024];
    short (*P_lds)[2][4][16][8] = (short (*)[2][4][16][8])smem; // [wave][tile][kgrp][q][8]
    float (*O_lds)[16][64]      = (float (*)[16][64])smem;      // [wave][q][h]
    float (*M_lds)[16] = (float (*)[16])(smem + 32768);         // [wave][q]
    float (*L_lds)[16] = (float (*)[16])(smem + 32768 + 512);

    // per-lane mask bits: tile0 q = qbase+c, tile1 q = qbase+16+c
    const unsigned int* pw0 = packed + (size_t)(b * SEQ + qbase + c) * 64 + w * 8;
    unsigned int mw0[8], mw1[8];
    #pragma unroll
    for (int i = 0; i < 8; ++i) { mw0[i] = pw0[i]; mw1[i] = pw0[16 * 64 + i]; }

    // Q as B-operand fragments for both tiles
    bf16x8 qb0 = *(const bf16x8*)&Qb[c * HEAD + g * 8];
    bf16x8 qb1 = *(const bf16x8*)&Qb[c * HEAD + 32 + g * 8];
    bf16x8 qc0 = *(const bf16x8*)&Qb[(16 + c) * HEAD + g * 8];
    bf16x8 qc1 = *(const bf16x8*)&Qb[(16 + c) * HEAD + 32 + g * 8];

    float m0 = -INFINITY, l0 = 0.0f, m1 = -INFINITY, l1 = 0.0f;
    f32x4 o0[4], o1[4];
    #pragma unroll
    for (int n = 0; n < 4; ++n) { o0[n] = (f32x4)0.0f; o1[n] = (f32x4)0.0f; }

    const float scale = 0.125f;                    // HEAD^-0.5
    const float LOG2E = 1.44269504088896340736f;

    for (int i = 0; i < 8; ++i) {
        const int kt = w * 8 + i;                  // key tile of 32
        const short* Kt = Kb + (size_t)kt * 32 * HEAD;

        // V^T B-fragments (shared by both q-tiles)
        bf16x8 vb[4];
        #pragma unroll
        for (int n = 0; n < 4; ++n)
            vb[n] = *(const bf16x8*)&Vb[(size_t)(n * 16 + c) * SEQ + kt * 32 + g * 8];

        // K as A-operand (shared by both q-tiles)
        bf16x8 ka00 = *(const bf16x8*)&Kt[c * HEAD + g * 8];
        bf16x8 ka01 = *(const bf16x8*)&Kt[c * HEAD + 32 + g * 8];
        bf16x8 ka10 = *(const bf16x8*)&Kt[(16 + c) * HEAD + g * 8];
        bf16x8 ka11 = *(const bf16x8*)&Kt[(16 + c) * HEAD + 32 + g * 8];

        // ---- both tiles' QK^T (K frags reused) ----
        f32x4 s0t0 = (f32x4)0.0f, s1t0 = (f32x4)0.0f;
        s0t0 = __builtin_amdgcn_mfma_f32_16x16x32_bf16(ka00, qb0, s0t0, 0, 0, 0);
        s0t0 = __builtin_amdgcn_mfma_f32_16x16x32_bf16(ka01, qb1, s0t0, 0, 0, 0);
        s1t0 = __builtin_amdgcn_mfma_f32_16x16x32_bf16(ka10, qb0, s1t0, 0, 0, 0);
        s1t0 = __builtin_amdgcn_mfma_f32_16x16x32_bf16(ka11, qb1, s1t0, 0, 0, 0);
        f32x4 s0t1 = (f32x4)0.0f, s1t1 = (f32x4)0.0f;
        s0t1 = __builtin_amdgcn_mfma_f32_16x16x32_bf16(ka00, qc0, s0t1, 0, 0, 0);
        s0t1 = __builtin_amdgcn_mfma_f32_16x16x32_bf16(ka01, qc1, s0t1, 0, 0, 0);
        s1t1 = __builtin_amdgcn_mfma_f32_16x16x32_bf16(ka10, qc0, s1t1, 0, 0, 0);
        s1t1 = __builtin_amdgcn_mfma_f32_16x16x32_bf16(ka11, qc1, s1t1, 0, 0, 0);

        // ---- per-tile softmax + PV ----
        #pragma unroll
        for (int t = 0; t < 2; ++t) {
            const f32x4 s0 = t ? s0t1 : s0t0;
            const f32x4 s1 = t ? s1t1 : s1t0;
            const unsigned int mw32 = t ? mw1[i] : mw0[i];
            float& m_run = t ? m1 : m0;
            float& l_run = t ? l1 : l0;
            f32x4* o = t ? o1 : o0;

            float sv[8];
            #pragma unroll
            for (int r = 0; r < 4; ++r) {
                sv[r]     = ((mw32 >> (g * 4 + r)) & 1u)      ? -INFINITY : s0[r] * scale;
                sv[4 + r] = ((mw32 >> (16 + g * 4 + r)) & 1u) ? -INFINITY : s1[r] * scale;
            }

            float mx = fmaxf(fmaxf(fmaxf(sv[0], sv[1]), fmaxf(sv[2], sv[3])),
                             fmaxf(fmaxf(sv[4], sv[5]), fmaxf(sv[6], sv[7])));
            mx = fmaxf(mx, __shfl_xor(mx, 16));
            mx = fmaxf(mx, __shfl_xor(mx, 32));

            if (!__all(mx <= m_run + 8.0f)) {
                float mn = fmaxf(m_run, mx);
                float cf = (m_run == mn) ? 1.0f : exp2f((m_run - mn) * LOG2E);
                float cfq[4];
                #pragma unroll
                for (int r = 0; r < 4; ++r)
                    cfq[r] = __shfl(cf, (lane & 48) | (g * 4 + r));
                #pragma unroll
                for (int n = 0; n < 4; ++n)
                    #pragma unroll
                    for (int r = 0; r < 4; ++r) o[n][r] *= cfq[r];
                l_run *= cf;
                m_run = mn;
            }

            const float mb = m_run * LOG2E;
            float p[8];
            #pragma unroll
            for (int j = 0; j < 8; ++j)
                p[j] = (sv[j] <= -1e37f) ? 0.0f : exp2f(sv[j] * LOG2E - mb);
            float rs = ((p[0] + p[1]) + (p[2] + p[3])) + ((p[4] + p[5]) + (p[6] + p[7]));
            rs += __shfl_xor(rs, 16);
            rs += __shfl_xor(rs, 32);
            l_run += rs;

            bf16x4 p0v, p1v;
            #pragma unroll
            for (int r = 0; r < 4; ++r) { p0v[r] = f2bf(p[r]); p1v[r] = f2bf(p[4 + r]); }
            *(bf16x4*)&P_lds[w][t][g >> 1][c][(g & 1) * 4]       = p0v;
            *(bf16x4*)&P_lds[w][t][2 + (g >> 1)][c][(g & 1) * 4] = p1v;
            bf16x8 pa = *(bf16x8*)&P_lds[w][t][g][c][0];
            #pragma unroll
            for (int n = 0; n < 4; ++n)
                o[n] = __builtin_amdgcn_mfma_f32_16x16x32_bf16(pa, vb[n], o[n], 0, 0, 0);
        }
    }

    // ---- merge: tile0 then tile1 through the same 32KB buffer ----
    const int row  = tid >> 5;
    const int col0 = (tid & 31) * 2;
    float* Ob0 = out + (size_t)(b * SEQ + qbase + row) * HEAD;
    float* Ob1 = out + (size_t)(b * SEQ + qbase + 16 + row) * HEAD;

    #pragma unroll
    for (int t = 0; t < 2; ++t) {
        __syncthreads();   // P reads done (t=0) / previous merge reads done (t=1)
        const f32x4* o = t ? o1 : o0;
        #pragma unroll
        for (int n = 0; n < 4; ++n)
            #pragma unroll
            for (int r = 0; r < 4; ++r)
                O_lds[w][g * 4 + r][n * 16 + c] = o[n][r];
        if (lane < 16) {
            M_lds[w][lane] = t ? m1 : m0;
            L_lds[w][lane] = t ? l1 : l0;
        }
        __syncthreads();

        float M = -INFINITY;
        #pragma unroll
        for (int i = 0; i < 8; ++i) M = fmaxf(M, M_lds[i][row]);
        float L = 0.0f, a0 = 0.0f, a1 = 0.0f;
        #pragma unroll
        for (int i = 0; i < 8; ++i) {
            float wgt = exp2f((M_lds[i][row] - M) * LOG2E);
            L  += L_lds[i][row] * wgt;
            a0 += O_lds[i][row][col0]     * wgt;
            a1 += O_lds[i][row][col0 + 1] * wgt;
        }
        float inv = 1.0f / L;
        float* Ob = t ? Ob1 : Ob0;
        Ob[col0]     = a0 * inv;
        Ob[col0 + 1] = a1 * inv;
    }
}

extern "C" void kernel_launch(void* const* d_in, const int* in_sizes, int n_in,
                              void* d_out, int out_size, void* d_ws, size_t ws_size,
                              hipStream_t stream)
{
    // setup_inputs order: key_input, query_input, value_input, mask, Wq, Wk, Wv
    const float* key_in   = (const float*)d_in[0];
    const float* query_in = (const float*)d_in[1];
    const float* value_in = (const float*)d_in[2];
    const void*  mask     = d_in[3];
    const float* Wq = (const float*)d_in[4];
    const float* Wk = (const float*)d_in[5];
    const float* Wv = (const float*)d_in[6];

    char* ws = (char*)d_ws;
    short* Qw  = (short*)ws;                            // 1 MB
    short* Kw  = Qw + (size_t)BATCH * SEQ * HEAD;       // 1 MB
    short* Vtw = Kw + (size_t)BATCH * SEQ * HEAD;       // 1 MB
    unsigned long long* packed =
        (unsigned long long*)(ws + (size_t)3 * BATCH * SEQ * HEAD * sizeof(short));  // 2 MB
    short* Wt  = (short*)((char*)packed + (size_t)NCHUNK * 8);   // 384 KB
    int* mflag = (int*)((char*)Wt + (size_t)3 * HEAD * DIM * sizeof(short));

    wconv_detect_kernel<<<dim3(16, 3), 256, 0, stream>>>(
        Wq, Wk, Wv, Wt, (const unsigned int*)mask, mflag);

    prep_kernel<<<1280, 256, 0, stream>>>(
        query_in, key_in, value_in, Wt, mask, mflag, packed, Qw, Kw, Vtw);

    attn_kernel<<<256, 512, 0, stream>>>(
        Qw, Kw, Vtw, (const unsigned int*)packed, (float*)d_out);
}